// Round 20
// baseline (254.896 us; speedup 1.0000x reference)
//
#include <hip/hip_runtime.h>
#include <stdint.h>

#define DMODEL 1024
#define NHEAD 16
#define DH 64
#define BB 4
#define SS 2048
#define MROWS (BB * SS)   // 8192

typedef __bf16 bfx8 __attribute__((ext_vector_type(8)));
typedef float f32x4 __attribute__((ext_vector_type(4)));
typedef float fvec4 __attribute__((ext_vector_type(4)));
typedef int i32x4 __attribute__((ext_vector_type(4)));
typedef unsigned short u16x8 __attribute__((ext_vector_type(8)));
typedef unsigned short u16x4 __attribute__((ext_vector_type(4)));

__device__ __forceinline__ unsigned short f2bf(float f) {
    union { float f; unsigned int u; } v; v.f = f;
    unsigned int r = v.u + 0x7FFFu + ((v.u >> 16) & 1u);
    return (unsigned short)(r >> 16);
}

// packed fp32x2 -> bf16x2 (RNE), single HW instruction
__device__ __forceinline__ unsigned int cvtpk(float lo, float hi) {
    unsigned int r;
    asm("v_cvt_pk_bf16_f32 %0, %1, %2" : "=v"(r) : "v"(lo), "v"(hi));
    return r;
}

// async global->LDS, 16B per lane. LDS dest must be linear: wave base + lane*16.
typedef __attribute__((address_space(1))) const void gas_t;
typedef __attribute__((address_space(3))) void las_t;
__device__ __forceinline__ void gload_lds16(const void* g, void* l) {
    __builtin_amdgcn_global_load_lds((gas_t*)g, (las_t*)l, 16, 0, 0);
}

// K-row permutation for swapped-QK in-register P trick.
// i bits [nf1 nf0 lg1 lg0 r1 r0] -> sigma bits [nf1 lg1 lg0 nf0 r1 r0]
__device__ __forceinline__ int sigma_k(int i) {
    return (i & 0x20) | ((i & 0x0C) << 1) | ((i & 0x10) >> 2) | (i & 3);
}

// ---------------------------------------------------------------------------
// Transpose + convert: Wt[n][k] (bf16) = W[k][n] (fp32). 64x64 tiles.
// blockIdx.z selects which of FOUR weights (one launch for all).
// ---------------------------------------------------------------------------
__global__ void transpose_cvt4_kernel(const float* __restrict__ W0, unsigned short* __restrict__ T0,
                                      const float* __restrict__ W1, unsigned short* __restrict__ T1,
                                      const float* __restrict__ W2, unsigned short* __restrict__ T2,
                                      const float* __restrict__ W3, unsigned short* __restrict__ T3)
{
    const float* W = (blockIdx.z == 0) ? W0 : (blockIdx.z == 1) ? W1
                   : (blockIdx.z == 2) ? W2 : W3;
    unsigned short* Wt = (blockIdx.z == 0) ? T0 : (blockIdx.z == 1) ? T1
                       : (blockIdx.z == 2) ? T2 : T3;
    __shared__ unsigned short t[64][72];
    const int tid = threadIdx.x;
    const int r0 = blockIdx.y * 64, c0 = blockIdx.x * 64;
    #pragma unroll
    for (int i = 0; i < 4; ++i) {
        int idx = tid + i * 256;
        int r = idx >> 4, c4 = idx & 15;
        fvec4 v = *reinterpret_cast<const fvec4*>(&W[(size_t)(r0 + r) * DMODEL + c0 + c4 * 4]);
        #pragma unroll
        for (int j = 0; j < 4; ++j) t[c4 * 4 + j][r] = f2bf(v[j]);
    }
    __syncthreads();
    #pragma unroll
    for (int i = 0; i < 2; ++i) {
        int idx = tid + i * 256;
        int r = idx >> 3, c8 = idx & 7;
        u16x8 v = *reinterpret_cast<const u16x8*>(&t[r][c8 * 8]);
        *reinterpret_cast<u16x8*>(&Wt[(size_t)(c0 + r) * DMODEL + r0 + c8 * 8]) = v;
    }
}

// ---------------------------------------------------------------------------
// GEMM: out = A @ Bt^T + bias; Bt bf16 via global_load_lds.
// A_FP32 path: A fp32 reg-staged with fused v_cvt_pk_bf16_f32; sB is
// double-buffered so B(k+1) is issued one iteration early; the only vmem
// wait is the compiler's implicit wait on the A regs (full iteration of
// latency hiding). launch_bounds(256,3). Else A bf16 via global_load_lds,
// classic 2-barrier, launch_bounds(256,4).
// mode: 0 = bf16 row-major out, 2 = fp32 row-major out,
//       3 = bf16 Vt-layout out: O[((b*16+h)*64+d)*2048 + s] (per-head V^T)
// ---------------------------------------------------------------------------
struct GArg {
    const void* A;
    const unsigned short* Bt;
    const float* bias;
    void* O;
    float osc;
    int mode;
};

template<bool A_FP32>
__global__ __launch_bounds__(256, A_FP32 ? 3 : 4)
void gemm_kernel(GArg g0, GArg g1, GArg g2, int M, int N, int K)
{
    const GArg g = (blockIdx.z == 0) ? g0 : (blockIdx.z == 1) ? g1 : g2;
    __shared__ unsigned short sA[128 * 64];
    __shared__ unsigned short sB[(A_FP32 ? 2 : 1) * 128 * 64];
    const int tid  = threadIdx.x;
    const int lane = tid & 63;
    const int wave = tid >> 6;
    const int wm = (wave >> 1) * 64, wn = (wave & 1) * 64;
    const int m0 = blockIdx.x * 128, n0 = blockIdx.y * 128;
    const int lr = lane & 15;
    const int lg = lane >> 4;
    const int arow = tid >> 3, acol8 = tid & 7;   // A staging coords

    f32x4 acc[4][4] = {};
    fvec4 ar[4][2];                               // A(k) regs (fp32 path only)

    if constexpr (A_FP32) {
        // prologue: issue B(0) FIRST (so waiting on A(0) implies B(0) done),
        // then A(0) reg loads.
        #pragma unroll
        for (int i = 0; i < 4; ++i) {
            int c = tid + i * 256;
            int row = c >> 3, col8 = c & 7;
            gload_lds16(&g.Bt[(size_t)(n0 + row) * K + col8 * 8], &sB[c * 8]);
        }
        __builtin_amdgcn_sched_barrier(0);
        const float* Af = (const float*)g.A;
        #pragma unroll
        for (int i = 0; i < 4; ++i) {
            const float* src = &Af[(size_t)(m0 + arow + i * 32) * K + acol8 * 8];
            ar[i][0] = *reinterpret_cast<const fvec4*>(src);
            ar[i][1] = *reinterpret_cast<const fvec4*>(src + 4);
        }
        __builtin_amdgcn_sched_barrier(0);
    }

    for (int kk0 = 0; kk0 < K; kk0 += 64) {
        if constexpr (A_FP32) {
            const int cur = (kk0 >> 6) & 1;
            const bool more = (kk0 + 64 < K);
            // ---- barrier: all waves done computing from sA(k-1)/sB
            __builtin_amdgcn_sched_barrier(0);
            __builtin_amdgcn_s_barrier();
            __builtin_amdgcn_sched_barrier(0);
            // ---- write A(kk0) from regs (compiler waits vmcnt for ar here;
            //      in-order completion => B(kk0) also landed in sB[cur])
            #pragma unroll
            for (int i = 0; i < 4; ++i) {
                union { i32x4 i4; u16x8 u; } pk;
                pk.i4[0] = cvtpk(ar[i][0][0], ar[i][0][1]);
                pk.i4[1] = cvtpk(ar[i][0][2], ar[i][0][3]);
                pk.i4[2] = cvtpk(ar[i][1][0], ar[i][1][1]);
                pk.i4[3] = cvtpk(ar[i][1][2], ar[i][1][3]);
                *reinterpret_cast<u16x8*>(&sA[(arow + i * 32) * 64 + acol8 * 8]) = pk.u;
            }
            __builtin_amdgcn_sched_barrier(0);
            // ---- issue B(kk0+64) into the other buffer (flies across barrier)
            if (more) {
                #pragma unroll
                for (int i = 0; i < 4; ++i) {
                    int c = tid + i * 256;
                    int row = c >> 3, col8 = c & 7;
                    gload_lds16(&g.Bt[(size_t)(n0 + row) * K + kk0 + 64 + col8 * 8],
                                &sB[(cur ^ 1) * 8192 + c * 8]);
                }
            }
            __builtin_amdgcn_sched_barrier(0);
            // ---- issue A(kk0+64) loads (after B, preserving queue order)
            if (more) {
                const float* Af = (const float*)g.A;
                #pragma unroll
                for (int i = 0; i < 4; ++i) {
                    const float* src = &Af[(size_t)(m0 + arow + i * 32) * K + kk0 + 64 + acol8 * 8];
                    ar[i][0] = *reinterpret_cast<const fvec4*>(src);
                    ar[i][1] = *reinterpret_cast<const fvec4*>(src + 4);
                }
            }
            __builtin_amdgcn_sched_barrier(0);
            // ---- only the ds_writes must be visible; B(k+1)/A(k+1) stay in flight
            asm volatile("s_waitcnt lgkmcnt(0)" ::: "memory");
            __builtin_amdgcn_sched_barrier(0);
            __builtin_amdgcn_s_barrier();
            __builtin_amdgcn_sched_barrier(0);

            const unsigned short* sBc = &sB[cur * 8192];
            #pragma unroll
            for (int kk = 0; kk < 2; ++kk) {
                bfx8 af[4], bfr[4];
                #pragma unroll
                for (int m = 0; m < 4; ++m)
                    af[m] = *reinterpret_cast<const bfx8*>(
                        &sA[(wm + m * 16 + lr) * 64 + kk * 32 + lg * 8]);
                #pragma unroll
                for (int n = 0; n < 4; ++n)
                    bfr[n] = *reinterpret_cast<const bfx8*>(
                        &sBc[(wn + n * 16 + lr) * 64 + kk * 32 + lg * 8]);
                #pragma unroll
                for (int m = 0; m < 4; ++m)
                    #pragma unroll
                    for (int n = 0; n < 4; ++n)
                        acc[m][n] = __builtin_amdgcn_mfma_f32_16x16x32_bf16(
                            af[m], bfr[n], acc[m][n], 0, 0, 0);
            }
        } else {
            __syncthreads();
            #pragma unroll
            for (int i = 0; i < 4; ++i) {
                int c = tid + i * 256;
                int row = c >> 3, col8 = c & 7;
                gload_lds16(&((const unsigned short*)g.A)[(size_t)(m0 + row) * K + kk0 + col8 * 8],
                            &sA[c * 8]);
            }
            #pragma unroll
            for (int i = 0; i < 4; ++i) {
                int c = tid + i * 256;
                int row = c >> 3, col8 = c & 7;
                gload_lds16(&g.Bt[(size_t)(n0 + row) * K + kk0 + col8 * 8], &sB[c * 8]);
            }
            __syncthreads();

            #pragma unroll
            for (int kk = 0; kk < 2; ++kk) {
                bfx8 af[4], bfr[4];
                #pragma unroll
                for (int m = 0; m < 4; ++m)
                    af[m] = *reinterpret_cast<const bfx8*>(
                        &sA[(wm + m * 16 + lr) * 64 + kk * 32 + lg * 8]);
                #pragma unroll
                for (int n = 0; n < 4; ++n)
                    bfr[n] = *reinterpret_cast<const bfx8*>(
                        &sB[(wn + n * 16 + lr) * 64 + kk * 32 + lg * 8]);
                #pragma unroll
                for (int m = 0; m < 4; ++m)
                    #pragma unroll
                    for (int n = 0; n < 4; ++n)
                        acc[m][n] = __builtin_amdgcn_mfma_f32_16x16x32_bf16(
                            af[m], bfr[n], acc[m][n], 0, 0, 0);
            }
        }
    }

    #pragma unroll
    for (int n = 0; n < 4; ++n) {
        int col = n0 + wn + n * 16 + lr;
        float bv = g.bias[col];
        #pragma unroll
        for (int m = 0; m < 4; ++m) {
            int rowb = m0 + wm + m * 16 + lg * 4;
            float val[4];
            #pragma unroll
            for (int r = 0; r < 4; ++r) val[r] = (acc[m][n][r] + bv) * g.osc;
            if (g.mode == 0) {
                #pragma unroll
                for (int r = 0; r < 4; ++r)
                    ((unsigned short*)g.O)[(size_t)(rowb + r) * N + col] = f2bf(val[r]);
            } else if (g.mode == 2) {
                #pragma unroll
                for (int r = 0; r < 4; ++r)
                    ((float*)g.O)[(size_t)(rowb + r) * N + col] = val[r];
            } else {
                // Vt layout: rows rowb..rowb+3 are consecutive s in one batch
                int bq = rowb >> 11, s = rowb & 2047;
                int hh = col >> 6, d = col & 63;
                u16x4 pk;
                #pragma unroll
                for (int r = 0; r < 4; ++r) pk[r] = f2bf(val[r]);
                size_t idx = ((size_t)(bq * 16 + hh) * 64 + d) * 2048 + s;
                *reinterpret_cast<u16x4*>(&((unsigned short*)g.O)[idx]) = pk;
            }
        }
    }
}

// ---------------------------------------------------------------------------
// Flash-style causal attention. 8-wave (512-thr) blocks, QBLK=128, wave owns
// 16 q-rows; balanced q-tile pair {15-p, p} sequential (ph loop).
// Single-barrier double-buffered 2-tile LDS pairs. Per pair: QK^T for BOTH
// tiles first (sc[8]), then ONE merged guard/mask/exp2 pass, then PV.
// l via ones-MFMA (C-layout, shuffle-free epilogue); in-register P.
// Q pre-scaled by 1/sqrt(2048)*log2(e). Q,K: [B*S][H*DH]; Vt: [B*H][DH][S].
// ---------------------------------------------------------------------------
__global__ __launch_bounds__(512, 4)
void attn_kernel(const unsigned short* __restrict__ Q,
                 const unsigned short* __restrict__ K,
                 const unsigned short* __restrict__ Vt,
                 unsigned short* __restrict__ C)
{
    __shared__ unsigned short sK[2][8192];   // [pairbuf][tile s*4096 + off]
    __shared__ unsigned short sV[2][8192];

    const int tid  = threadIdx.x;                // 0..511
    const int lane = tid & 63;
    const int wave = tid >> 6;                   // 0..7
    const int lr = lane & 15, lg = lane >> 4;
    const int bh = blockIdx.x;
    const int p  = blockIdx.y;                   // pair index 0..7
    const int b = bh >> 4, h = bh & 15;
    const size_t rowbase = (size_t)b * SS;
    const int hcol = h * DH;

    // staging coords: one 8-elem chunk per thread (64 rows x 8 chunks = 512)
    const int srow = tid >> 3, sc8 = tid & 7;
    const int sig  = sigma_k(srow);
    const int woff = srow * 64 + ((sc8 ^ (srow & 7)) * 8);
    const int p0 = lg ^ (lr & 7);                // swizzled chunk for QK reads

    const u16x8 onesu = {0x3F80, 0x3F80, 0x3F80, 0x3F80, 0x3F80, 0x3F80, 0x3F80, 0x3F80};
    union { u16x8 u; bfx8 b; } onesc; onesc.u = onesu;
    const bfx8 ones = onesc.b;

    #pragma unroll
    for (int ph = 0; ph < 2; ++ph) {
        const int qt = ph ? p : (15 - p);
        const int q0 = qt * 128;

        // Q fragment: wave's 16 q-rows, 2 d-chunks (B-operand of swapped mfma)
        bfx8 aq[2];
        {
            int qr = q0 + wave * 16 + lr;
            const unsigned short* qp = &Q[(rowbase + qr) * DMODEL + hcol + lg * 8];
            aq[0] = *reinterpret_cast<const bfx8*>(qp);
            aq[1] = *reinterpret_cast<const bfx8*>(qp + 32);
        }

        float m_run = 0.f;                       // per-lane (q = lr), exp2 domain
        f32x4 acc_l = {};                        // l in C-layout (row = lg*4+r)
        f32x4 acc_o[4] = {};
        bool mz = true;
        const int qmax_wave = q0 + wave * 16 + 15;
        const int npairs = qt + 1;               // k-tiles = 2*npairs

        u16x8 rk[2], rv[2];
        // ---- prologue: pair 0 -> regs -> buf0; then issue pair-1 loads
        #pragma unroll
        for (int s = 0; s < 2; ++s) {
            rk[s] = *reinterpret_cast<const u16x8*>(
                &K[(rowbase + s * 64 + sig) * DMODEL + hcol + sc8 * 8]);
            rv[s] = *reinterpret_cast<const u16x8*>(
                &Vt[((size_t)bh * DH + srow) * SS + s * 64 + sc8 * 8]);
        }
        #pragma unroll
        for (int s = 0; s < 2; ++s) {
            *reinterpret_cast<u16x8*>(&sK[0][s * 4096 + woff]) = rk[s];
            *reinterpret_cast<u16x8*>(&sV[0][s * 4096 + woff]) = rv[s];
        }
        if (npairs > 1) {
            #pragma unroll
            for (int s = 0; s < 2; ++s) {
                const int kk = (2 + s) * 64;
                rk[s] = *reinterpret_cast<const u16x8*>(
                    &K[(rowbase + kk + sig) * DMODEL + hcol + sc8 * 8]);
                rv[s] = *reinterpret_cast<const u16x8*>(
                    &Vt[((size_t)bh * DH + srow) * SS + kk + sc8 * 8]);
            }
        }
        __syncthreads();

        for (int u = 0; u < npairs; ++u) {
            const int cur = u & 1;
            const int k0p = 2 * u * 64;          // first tile's k0
            // how many of the 2 tiles are live for this wave?
            const int nlive = (k0p + 64 > qmax_wave) ? 1 : 2;  // tile0 always live (k0p <= qmax by loop bound)

            // ---- QK^T for all live tiles (big MFMA cluster)
            f32x4 sc[2][4];
            __builtin_amdgcn_s_setprio(1);
            for (int s = 0; s < nlive; ++s) {
                #pragma unroll
                for (int nf = 0; nf < 4; ++nf) {
                    int i = nf * 16 + lr;
                    bfx8 ak0 = *reinterpret_cast<const bfx8*>(&sK[cur][s * 4096 + i * 64 + p0 * 8]);
                    bfx8 ak1 = *reinterpret_cast<const bfx8*>(&sK[cur][s * 4096 + i * 64 + (p0 ^ 4) * 8]);
                    f32x4 sv = {0.f, 0.f, 0.f, 0.f};
                    sv = __builtin_amdgcn_mfma_f32_16x16x32_bf16(ak0, aq[0], sv, 0, 0, 0);
                    sv = __builtin_amdgcn_mfma_f32_16x16x32_bf16(ak1, aq[1], sv, 0, 0, 0);
                    sc[s][nf] = sv;
                }
            }
            __builtin_amdgcn_s_setprio(0);
            // ---- causal mask (only diagonal-overlapping tiles do work)
            for (int s = 0; s < nlive; ++s) {
                const int k0 = k0p + s * 64;
                if (k0 + 63 > q0 + wave * 16) {
                    int qrow = q0 + wave * 16 + lr;
                    #pragma unroll
                    for (int nf = 0; nf < 4; ++nf) {
                        int kb = k0 + ((nf >> 1) << 5) + (lg << 3) + ((nf & 1) << 2);
                        #pragma unroll
                        for (int r = 0; r < 4; ++r)
                            if (kb + r > qrow) sc[s][nf][r] = -3.0e38f;
                    }
                }
            }
            // ---- ONE merged guard over all live scores
            float pmax = -3.0e38f;
            for (int s = 0; s < nlive; ++s) {
                float a0 = fmaxf(fmaxf(sc[s][0][0], sc[s][0][1]), sc[s][0][2]);
                float a1 = fmaxf(fmaxf(sc[s][0][3], sc[s][1][0]), sc[s][1][1]);
                float a2 = fmaxf(fmaxf(sc[s][1][2], sc[s][1][3]), sc[s][2][0]);
                float a3 = fmaxf(fmaxf(sc[s][2][1], sc[s][2][2]), sc[s][2][3]);
                float a4 = fmaxf(fmaxf(sc[s][3][0], sc[s][3][1]), sc[s][3][2]);
                pmax = fmaxf(pmax, fmaxf(fmaxf(fmaxf(a0, a1), fmaxf(a2, a3)),
                                         fmaxf(a4, sc[s][3][3])));
            }
            if (mz && __all(pmax <= 8.0f)) {
                for (int s = 0; s < nlive; ++s)
                    #pragma unroll
                    for (int nf = 0; nf < 4; ++nf)
                        #pragma unroll
                        for (int r = 0; r < 4; ++r)
                            sc[s][nf][r] = __builtin_exp2f(sc[s][nf][r]);
            } else {
                mz = false;
                float mx = pmax;
                mx = fmaxf(mx, __shfl_xor(mx, 16, 64));
                mx = fmaxf(mx, __shfl_xor(mx, 32, 64));
                float mnew = fmaxf(m_run, mx);
                float fs = __builtin_exp2f(m_run - mnew);
                m_run = mnew;
                for (int s = 0; s < nlive; ++s)
                    #pragma unroll
                    for (int nf = 0; nf < 4; ++nf)
                        #pragma unroll
                        for (int r = 0; r < 4; ++r)
                            sc[s][nf][r] = __builtin_exp2f(sc[s][nf][r] - mnew);
                #pragma unroll
                for (int r = 0; r < 4; ++r) {
                    float fsa = __shfl(fs, lg * 4 + r, 64);
                    #pragma unroll
                    for (int d = 0; d < 4; ++d) acc_o[d][r] *= fsa;
                    acc_l[r] *= fsa;
                }
            }
            // ---- pack P in-register; PV + l via MFMA
            for (int s = 0; s < nlive; ++s) {
                #pragma unroll
                for (int h2 = 0; h2 < 2; ++h2) {
                    union { i32x4 i; bfx8 b; } pa;
                    pa.i[0] = cvtpk(sc[s][2 * h2][0],     sc[s][2 * h2][1]);
                    pa.i[1] = cvtpk(sc[s][2 * h2][2],     sc[s][2 * h2][3]);
                    pa.i[2] = cvtpk(sc[s][2 * h2 + 1][0], sc[s][2 * h2 + 1][1]);
                    pa.i[3] = cvtpk(sc[s][2 * h2 + 1][2], sc[s][2 * h2 + 1][3]);
                    __builtin_amdgcn_s_setprio(1);
                    acc_l = __builtin_amdgcn_mfma_f32_16x16x32_bf16(pa.b, ones, acc_l, 0, 0, 0);
                    #pragma unroll
                    for (int d = 0; d < 4; ++d) {
                        int i = d * 16 + lr;
                        int pv = ((h2 << 2) | lg) ^ (lr & 7);
                        bfx8 bv0 = *reinterpret_cast<const bfx8*>(&sV[cur][s * 4096 + i * 64 + pv * 8]);
                        acc_o[d] = __builtin_amdgcn_mfma_f32_16x16x32_bf16(pa.b, bv0, acc_o[d], 0, 0, 0);
                    }
                    __builtin_amdgcn_s_setprio(0);
                }
            }
            // ---- write pair u+1 into the other buffer, issue loads for u+2
            if (u + 1 < npairs) {
                #pragma unroll
                for (int s = 0; s < 2; ++s) {
                    *reinterpret_cast<u16x8*>(&sK[cur ^ 1][s * 4096 + woff]) = rk[s];
                    *reinterpret_cast<u16x8*>(&sV[cur ^ 1][s * 4096 + woff]) = rv[s];
                }
                if (u + 2 < npairs) {
                    #pragma unroll
                    for (int s = 0; s < 2; ++s) {
                        const int kk = (2 * u + 4 + s) * 64;
                        rk[s] = *reinterpret_cast<const u16x8*>(
                            &K[(rowbase + kk + sig) * DMODEL + hcol + sc8 * 8]);
                        rv[s] = *reinterpret_cast<const u16x8*>(
                            &Vt[((size_t)bh * DH + srow) * SS + kk + sc8 * 8]);
                    }
                }
            }
            __syncthreads();
        }

        // ---- epilogue: shuffle-free (acc_l shares acc_o's C-layout rows)
        f32x4 linv;
        #pragma unroll
        for (int r = 0; r < 4; ++r) linv[r] = 1.0f / acc_l[r];
        const int qrb = q0 + wave * 16 + lg * 4;
        #pragma unroll
        for (int d = 0; d < 4; ++d) {
            int col = hcol + d * 16 + lr;
            #pragma unroll
            for (int r = 0; r < 4; ++r)
                C[(rowbase + qrb + r) * DMODEL + col] = f2bf(acc_o[d][r] * linv[r]);
        }
    }
}

// ---------------------------------------------------------------------------
extern "C" void kernel_launch(void* const* d_in, const int* in_sizes, int n_in,
                              void* d_out, int out_size, void* d_ws, size_t ws_size,
                              hipStream_t stream)
{
    const float* q  = (const float*)d_in[0];
    const float* k  = (const float*)d_in[1];
    const float* v  = (const float*)d_in[2];
    const float* Wq = (const float*)d_in[3];
    const float* bq = (const float*)d_in[4];
    const float* Wk = (const float*)d_in[5];
    const float* bk = (const float*)d_in[6];
    const float* Wv = (const float*)d_in[7];
    const float* bv = (const float*)d_in[8];
    const float* Wf = (const float*)d_in[9];
    const float* bf = (const float*)d_in[10];

    unsigned short* ws = (unsigned short*)d_ws;
    const size_t SZ = (size_t)MROWS * DMODEL;        // 8388608 elems
    unsigned short* Vt = ws;                         // [0, SZ)   V^T per head
    unsigned short* Cb = ws + SZ;                    // [SZ, 2SZ) attn out
    unsigned short* Kb = ws + 3 * SZ;                // [3SZ,4SZ) K projection

    unsigned short* scr = (unsigned short*)d_out;    // d_out as scratch (16M ushorts)
    unsigned short* WqT = scr;                       // [0,1M)
    unsigned short* WkT = scr + 1048576;             // [1M,2M)
    unsigned short* WvT = scr + 2097152;             // [2M,3M)
    unsigned short* WfT = scr + 3145728;             // [3M,4M)
    unsigned short* Qb  = scr + 4194304;             // [4M,12M)

    const float qscale = 0.02209708691207961f * 1.44269504088896341f;

    // 1. all four weight transposes in one launch
    transpose_cvt4_kernel<<<dim3(16, 16, 4), 256, 0, stream>>>(
        Wq, WqT, Wk, WkT, Wv, WvT, Wf, WfT);

    // 2. Q, K, V projections in ONE z=3 launch, fp32 A with fused convert,
    //    async A prefetch, and double-buffered B staging.
    {
        GArg gq{q, WqT, bq, Qb, qscale, 0};
        GArg gk{k, WkT, bk, Kb, 1.0f,   0};
        GArg gv{v, WvT, bv, Vt, 1.0f,   3};
        gemm_kernel<true><<<dim3(64, 8, 3), 256, 0, stream>>>(
            gq, gk, gv, MROWS, DMODEL, DMODEL);
    }

    // 3. attention: Qb, Kb, Vt -> Cb
    attn_kernel<<<dim3(BB * NHEAD, 8), 512, 0, stream>>>(Qb, Kb, Vt, Cb);

    // 4. output projection: Cb @ WfT + bf -> d_out fp32 (scratch regions dead)
    {
        GArg gf{Cb, WfT, bf, (float*)d_out, 1.0f, 2};
        gemm_kernel<false><<<dim3(64, 8, 1), 256, 0, stream>>>(
            gf, gf, gf, MROWS, DMODEL, DMODEL);
    }
}

// Round 21
// 178.566 us; speedup vs baseline: 1.4275x; 1.4275x over previous
//
#include <hip/hip_runtime.h>
#include <stdint.h>

#define DMODEL 1024
#define NHEAD 16
#define DH 64
#define BB 4
#define SS 2048
#define MROWS (BB * SS)   // 8192

typedef __bf16 bfx8 __attribute__((ext_vector_type(8)));
typedef float f32x4 __attribute__((ext_vector_type(4)));
typedef float fvec4 __attribute__((ext_vector_type(4)));
typedef int i32x4 __attribute__((ext_vector_type(4)));
typedef unsigned short u16x8 __attribute__((ext_vector_type(8)));
typedef unsigned short u16x4 __attribute__((ext_vector_type(4)));

__device__ __forceinline__ unsigned short f2bf(float f) {
    union { float f; unsigned int u; } v; v.f = f;
    unsigned int r = v.u + 0x7FFFu + ((v.u >> 16) & 1u);
    return (unsigned short)(r >> 16);
}

// packed fp32x2 -> bf16x2 (RNE), single HW instruction
__device__ __forceinline__ unsigned int cvtpk(float lo, float hi) {
    unsigned int r;
    asm("v_cvt_pk_bf16_f32 %0, %1, %2" : "=v"(r) : "v"(lo), "v"(hi));
    return r;
}

// async global->LDS, 16B per lane. LDS dest must be linear: wave base + lane*16.
typedef __attribute__((address_space(1))) const void gas_t;
typedef __attribute__((address_space(3))) void las_t;
__device__ __forceinline__ void gload_lds16(const void* g, void* l) {
    __builtin_amdgcn_global_load_lds((gas_t*)g, (las_t*)l, 16, 0, 0);
}

// K-row permutation for swapped-QK in-register P trick.
// i bits [nf1 nf0 lg1 lg0 r1 r0] -> sigma bits [nf1 lg1 lg0 nf0 r1 r0]
__device__ __forceinline__ int sigma_k(int i) {
    return (i & 0x20) | ((i & 0x0C) << 1) | ((i & 0x10) >> 2) | (i & 3);
}

// ---------------------------------------------------------------------------
// Transpose + convert: Wt[n][k] (bf16) = W[k][n] (fp32). 64x64 tiles.
// blockIdx.z selects which of FOUR weights (one launch for all).
// ---------------------------------------------------------------------------
__global__ void transpose_cvt4_kernel(const float* __restrict__ W0, unsigned short* __restrict__ T0,
                                      const float* __restrict__ W1, unsigned short* __restrict__ T1,
                                      const float* __restrict__ W2, unsigned short* __restrict__ T2,
                                      const float* __restrict__ W3, unsigned short* __restrict__ T3)
{
    const float* W = (blockIdx.z == 0) ? W0 : (blockIdx.z == 1) ? W1
                   : (blockIdx.z == 2) ? W2 : W3;
    unsigned short* Wt = (blockIdx.z == 0) ? T0 : (blockIdx.z == 1) ? T1
                       : (blockIdx.z == 2) ? T2 : T3;
    __shared__ unsigned short t[64][72];
    const int tid = threadIdx.x;
    const int r0 = blockIdx.y * 64, c0 = blockIdx.x * 64;
    #pragma unroll
    for (int i = 0; i < 4; ++i) {
        int idx = tid + i * 256;
        int r = idx >> 4, c4 = idx & 15;
        fvec4 v = *reinterpret_cast<const fvec4*>(&W[(size_t)(r0 + r) * DMODEL + c0 + c4 * 4]);
        #pragma unroll
        for (int j = 0; j < 4; ++j) t[c4 * 4 + j][r] = f2bf(v[j]);
    }
    __syncthreads();
    #pragma unroll
    for (int i = 0; i < 2; ++i) {
        int idx = tid + i * 256;
        int r = idx >> 3, c8 = idx & 7;
        u16x8 v = *reinterpret_cast<const u16x8*>(&t[r][c8 * 8]);
        *reinterpret_cast<u16x8*>(&Wt[(size_t)(c0 + r) * DMODEL + r0 + c8 * 8]) = v;
    }
}

// ---------------------------------------------------------------------------
// GEMM: out = A @ Bt^T + bias; Bt bf16 via global_load_lds.
// A_FP32 path: A fp32 reg-staged with fused v_cvt_pk_bf16_f32; sB is
// DOUBLE-BUFFERED so B(k+1) is issued one iteration early. The only vmem
// wait is the compiler's implicit wait on the A regs at cvtpk, which (by
// in-order vmcnt completion) also guarantees B(k) landed -- and it sits
// after a full MFMA block of latency hiding. launch_bounds(256,3)
// (acc in 64 AGPRs + 32-VGPR ar[] prefetch needs the 168-reg cap).
// Else A bf16 via global_load_lds, classic 2-barrier, launch_bounds(256,4).
// mode: 0 = bf16 row-major out, 2 = fp32 row-major out,
//       3 = bf16 Vt-layout out: O[((b*16+h)*64+d)*2048 + s] (per-head V^T)
// ---------------------------------------------------------------------------
struct GArg {
    const void* A;
    const unsigned short* Bt;
    const float* bias;
    void* O;
    float osc;
    int mode;
};

template<bool A_FP32>
__global__ __launch_bounds__(256, A_FP32 ? 3 : 4)
void gemm_kernel(GArg g0, GArg g1, GArg g2, int M, int N, int K)
{
    const GArg g = (blockIdx.z == 0) ? g0 : (blockIdx.z == 1) ? g1 : g2;
    __shared__ unsigned short sA[128 * 64];
    __shared__ unsigned short sB[(A_FP32 ? 2 : 1) * 128 * 64];
    const int tid  = threadIdx.x;
    const int lane = tid & 63;
    const int wave = tid >> 6;
    const int wm = (wave >> 1) * 64, wn = (wave & 1) * 64;
    const int m0 = blockIdx.x * 128, n0 = blockIdx.y * 128;
    const int lr = lane & 15;
    const int lg = lane >> 4;
    const int arow = tid >> 3, acol8 = tid & 7;   // A staging coords

    f32x4 acc[4][4] = {};
    fvec4 ar[4][2];                               // A(k) regs (fp32 path only)

    if constexpr (A_FP32) {
        // prologue: issue B(0) FIRST (so waiting on A(0) implies B(0) done),
        // then A(0) reg loads.
        #pragma unroll
        for (int i = 0; i < 4; ++i) {
            int c = tid + i * 256;
            int row = c >> 3, col8 = c & 7;
            gload_lds16(&g.Bt[(size_t)(n0 + row) * K + col8 * 8], &sB[c * 8]);
        }
        __builtin_amdgcn_sched_barrier(0);
        const float* Af = (const float*)g.A;
        #pragma unroll
        for (int i = 0; i < 4; ++i) {
            const float* src = &Af[(size_t)(m0 + arow + i * 32) * K + acol8 * 8];
            ar[i][0] = *reinterpret_cast<const fvec4*>(src);
            ar[i][1] = *reinterpret_cast<const fvec4*>(src + 4);
        }
        __builtin_amdgcn_sched_barrier(0);
    }

    for (int kk0 = 0; kk0 < K; kk0 += 64) {
        if constexpr (A_FP32) {
            const int cur = (kk0 >> 6) & 1;
            const bool more = (kk0 + 64 < K);
            // ---- barrier: all waves done computing from sA(k-1)/sB
            __builtin_amdgcn_sched_barrier(0);
            __builtin_amdgcn_s_barrier();
            __builtin_amdgcn_sched_barrier(0);
            // ---- write A(kk0) from regs (compiler waits vmcnt for ar here;
            //      in-order completion => B(kk0) also landed in sB[cur])
            #pragma unroll
            for (int i = 0; i < 4; ++i) {
                union { i32x4 i4; u16x8 u; } pk;
                pk.i4[0] = cvtpk(ar[i][0][0], ar[i][0][1]);
                pk.i4[1] = cvtpk(ar[i][0][2], ar[i][0][3]);
                pk.i4[2] = cvtpk(ar[i][1][0], ar[i][1][1]);
                pk.i4[3] = cvtpk(ar[i][1][2], ar[i][1][3]);
                *reinterpret_cast<u16x8*>(&sA[(arow + i * 32) * 64 + acol8 * 8]) = pk.u;
            }
            __builtin_amdgcn_sched_barrier(0);
            // ---- issue B(kk0+64) into the other buffer (flies across barrier)
            if (more) {
                #pragma unroll
                for (int i = 0; i < 4; ++i) {
                    int c = tid + i * 256;
                    int row = c >> 3, col8 = c & 7;
                    gload_lds16(&g.Bt[(size_t)(n0 + row) * K + kk0 + 64 + col8 * 8],
                                &sB[(cur ^ 1) * 8192 + c * 8]);
                }
            }
            __builtin_amdgcn_sched_barrier(0);
            // ---- issue A(kk0+64) loads (after B, preserving queue order)
            if (more) {
                const float* Af = (const float*)g.A;
                #pragma unroll
                for (int i = 0; i < 4; ++i) {
                    const float* src = &Af[(size_t)(m0 + arow + i * 32) * K + kk0 + 64 + acol8 * 8];
                    ar[i][0] = *reinterpret_cast<const fvec4*>(src);
                    ar[i][1] = *reinterpret_cast<const fvec4*>(src + 4);
                }
            }
            __builtin_amdgcn_sched_barrier(0);
            // ---- only the ds_writes must be visible; B(k+1)/A(k+1) stay in flight
            asm volatile("s_waitcnt lgkmcnt(0)" ::: "memory");
            __builtin_amdgcn_sched_barrier(0);
            __builtin_amdgcn_s_barrier();
            __builtin_amdgcn_sched_barrier(0);

            const unsigned short* sBc = &sB[cur * 8192];
            #pragma unroll
            for (int kk = 0; kk < 2; ++kk) {
                bfx8 af[4], bfr[4];
                #pragma unroll
                for (int m = 0; m < 4; ++m)
                    af[m] = *reinterpret_cast<const bfx8*>(
                        &sA[(wm + m * 16 + lr) * 64 + kk * 32 + lg * 8]);
                #pragma unroll
                for (int n = 0; n < 4; ++n)
                    bfr[n] = *reinterpret_cast<const bfx8*>(
                        &sBc[(wn + n * 16 + lr) * 64 + kk * 32 + lg * 8]);
                #pragma unroll
                for (int m = 0; m < 4; ++m)
                    #pragma unroll
                    for (int n = 0; n < 4; ++n)
                        acc[m][n] = __builtin_amdgcn_mfma_f32_16x16x32_bf16(
                            af[m], bfr[n], acc[m][n], 0, 0, 0);
            }
        } else {
            __syncthreads();
            #pragma unroll
            for (int i = 0; i < 4; ++i) {
                int c = tid + i * 256;
                int row = c >> 3, col8 = c & 7;
                gload_lds16(&((const unsigned short*)g.A)[(size_t)(m0 + row) * K + kk0 + col8 * 8],
                            &sA[c * 8]);
            }
            #pragma unroll
            for (int i = 0; i < 4; ++i) {
                int c = tid + i * 256;
                int row = c >> 3, col8 = c & 7;
                gload_lds16(&g.Bt[(size_t)(n0 + row) * K + kk0 + col8 * 8], &sB[c * 8]);
            }
            __syncthreads();

            #pragma unroll
            for (int kk = 0; kk < 2; ++kk) {
                bfx8 af[4], bfr[4];
                #pragma unroll
                for (int m = 0; m < 4; ++m)
                    af[m] = *reinterpret_cast<const bfx8*>(
                        &sA[(wm + m * 16 + lr) * 64 + kk * 32 + lg * 8]);
                #pragma unroll
                for (int n = 0; n < 4; ++n)
                    bfr[n] = *reinterpret_cast<const bfx8*>(
                        &sB[(wn + n * 16 + lr) * 64 + kk * 32 + lg * 8]);
                #pragma unroll
                for (int m = 0; m < 4; ++m)
                    #pragma unroll
                    for (int n = 0; n < 4; ++n)
                        acc[m][n] = __builtin_amdgcn_mfma_f32_16x16x32_bf16(
                            af[m], bfr[n], acc[m][n], 0, 0, 0);
            }
        }
    }

    #pragma unroll
    for (int n = 0; n < 4; ++n) {
        int col = n0 + wn + n * 16 + lr;
        float bv = g.bias[col];
        #pragma unroll
        for (int m = 0; m < 4; ++m) {
            int rowb = m0 + wm + m * 16 + lg * 4;
            float val[4];
            #pragma unroll
            for (int r = 0; r < 4; ++r) val[r] = (acc[m][n][r] + bv) * g.osc;
            if (g.mode == 0) {
                #pragma unroll
                for (int r = 0; r < 4; ++r)
                    ((unsigned short*)g.O)[(size_t)(rowb + r) * N + col] = f2bf(val[r]);
            } else if (g.mode == 2) {
                #pragma unroll
                for (int r = 0; r < 4; ++r)
                    ((float*)g.O)[(size_t)(rowb + r) * N + col] = val[r];
            } else {
                // Vt layout: rows rowb..rowb+3 are consecutive s in one batch
                int bq = rowb >> 11, s = rowb & 2047;
                int hh = col >> 6, d = col & 63;
                u16x4 pk;
                #pragma unroll
                for (int r = 0; r < 4; ++r) pk[r] = f2bf(val[r]);
                size_t idx = ((size_t)(bq * 16 + hh) * 64 + d) * 2048 + s;
                *reinterpret_cast<u16x4*>(&((unsigned short*)g.O)[idx]) = pk;
            }
        }
    }
}

// ---------------------------------------------------------------------------
// Flash-style causal attention (R15: single-barrier double-buffered pairs).
// 8-wave (512-thr) blocks, QBLK=128, wave owns 16 q-rows; balanced q-tile
// pair {15-p, p} processed sequentially. l via ones-MFMA; max3 pmax tree;
// swizzled conflict-free LDS; sigma-permuted K rows; in-register P.
// Q pre-scaled by 1/sqrt(2048)*log2(e). Q,K: [B*S][H*DH]; Vt: [B*H][DH][S].
// ---------------------------------------------------------------------------
__global__ __launch_bounds__(512, 4)
void attn_kernel(const unsigned short* __restrict__ Q,
                 const unsigned short* __restrict__ K,
                 const unsigned short* __restrict__ Vt,
                 unsigned short* __restrict__ C)
{
    __shared__ unsigned short sK[2][8192];   // [pairbuf][tile s*4096 + off]
    __shared__ unsigned short sV[2][8192];

    const int tid  = threadIdx.x;                // 0..511
    const int lane = tid & 63;
    const int wave = tid >> 6;                   // 0..7
    const int lr = lane & 15, lg = lane >> 4;
    const int bh = blockIdx.x;
    const int p  = blockIdx.y;                   // pair index 0..7
    const int b = bh >> 4, h = bh & 15;
    const size_t rowbase = (size_t)b * SS;
    const int hcol = h * DH;

    // staging coords: one 8-elem chunk per thread (64 rows x 8 chunks = 512)
    const int srow = tid >> 3, sc8 = tid & 7;
    const int sig  = sigma_k(srow);
    const int woff = srow * 64 + ((sc8 ^ (srow & 7)) * 8);
    const int p0 = lg ^ (lr & 7);                // swizzled chunk for QK reads

    const u16x8 onesu = {0x3F80, 0x3F80, 0x3F80, 0x3F80, 0x3F80, 0x3F80, 0x3F80, 0x3F80};
    union { u16x8 u; bfx8 b; } onesc; onesc.u = onesu;
    const bfx8 ones = onesc.b;

    #pragma unroll
    for (int ph = 0; ph < 2; ++ph) {
        const int qt = ph ? p : (15 - p);
        const int q0 = qt * 128;

        // Q fragment: wave's 16 q-rows, 2 d-chunks (B-operand of swapped mfma)
        bfx8 aq[2];
        {
            int qr = q0 + wave * 16 + lr;
            const unsigned short* qp = &Q[(rowbase + qr) * DMODEL + hcol + lg * 8];
            aq[0] = *reinterpret_cast<const bfx8*>(qp);
            aq[1] = *reinterpret_cast<const bfx8*>(qp + 32);
        }

        float m_run = 0.f;                       // per-lane (q = lr), exp2 domain
        f32x4 acc_l = {};                        // l in C-layout (row = lg*4+r)
        f32x4 acc_o[4] = {};
        bool mz = true;
        const int qmax_wave = q0 + wave * 16 + 15;
        const int npairs = qt + 1;               // k-tiles = 2*npairs

        u16x8 rk[2], rv[2];
        // ---- prologue: pair 0 -> regs -> buf0; then issue pair-1 loads
        #pragma unroll
        for (int s = 0; s < 2; ++s) {
            rk[s] = *reinterpret_cast<const u16x8*>(
                &K[(rowbase + s * 64 + sig) * DMODEL + hcol + sc8 * 8]);
            rv[s] = *reinterpret_cast<const u16x8*>(
                &Vt[((size_t)bh * DH + srow) * SS + s * 64 + sc8 * 8]);
        }
        #pragma unroll
        for (int s = 0; s < 2; ++s) {
            *reinterpret_cast<u16x8*>(&sK[0][s * 4096 + woff]) = rk[s];
            *reinterpret_cast<u16x8*>(&sV[0][s * 4096 + woff]) = rv[s];
        }
        if (npairs > 1) {
            #pragma unroll
            for (int s = 0; s < 2; ++s) {
                const int kk = (2 + s) * 64;
                rk[s] = *reinterpret_cast<const u16x8*>(
                    &K[(rowbase + kk + sig) * DMODEL + hcol + sc8 * 8]);
                rv[s] = *reinterpret_cast<const u16x8*>(
                    &Vt[((size_t)bh * DH + srow) * SS + kk + sc8 * 8]);
            }
        }
        __syncthreads();

        for (int u = 0; u < npairs; ++u) {
            const int cur = u & 1;
            // ---- compute both tiles of pair u from buf[cur]
            #pragma unroll
            for (int s = 0; s < 2; ++s) {
                const int k0 = (2 * u + s) * 64;
                if (k0 > qmax_wave) break;

                f32x4 sc[4];
                __builtin_amdgcn_s_setprio(1);
                #pragma unroll
                for (int nf = 0; nf < 4; ++nf) {
                    int i = nf * 16 + lr;
                    bfx8 ak0 = *reinterpret_cast<const bfx8*>(&sK[cur][s * 4096 + i * 64 + p0 * 8]);
                    bfx8 ak1 = *reinterpret_cast<const bfx8*>(&sK[cur][s * 4096 + i * 64 + (p0 ^ 4) * 8]);
                    f32x4 sv = {0.f, 0.f, 0.f, 0.f};
                    sv = __builtin_amdgcn_mfma_f32_16x16x32_bf16(ak0, aq[0], sv, 0, 0, 0);
                    sv = __builtin_amdgcn_mfma_f32_16x16x32_bf16(ak1, aq[1], sv, 0, 0, 0);
                    sc[nf] = sv;
                }
                __builtin_amdgcn_s_setprio(0);
                // causal mask (diagonal-overlapping tiles only)
                if (k0 + 63 > q0 + wave * 16) {
                    int qrow = q0 + wave * 16 + lr;
                    #pragma unroll
                    for (int nf = 0; nf < 4; ++nf) {
                        int kb = k0 + ((nf >> 1) << 5) + (lg << 3) + ((nf & 1) << 2);
                        #pragma unroll
                        for (int r = 0; r < 4; ++r)
                            if (kb + r > qrow) sc[nf][r] = -3.0e38f;
                    }
                }
                // pmax via max3-friendly triples
                float a0 = fmaxf(fmaxf(sc[0][0], sc[0][1]), sc[0][2]);
                float a1 = fmaxf(fmaxf(sc[0][3], sc[1][0]), sc[1][1]);
                float a2 = fmaxf(fmaxf(sc[1][2], sc[1][3]), sc[2][0]);
                float a3 = fmaxf(fmaxf(sc[2][1], sc[2][2]), sc[2][3]);
                float a4 = fmaxf(fmaxf(sc[3][0], sc[3][1]), sc[3][2]);
                float pmax = fmaxf(fmaxf(fmaxf(a0, a1), fmaxf(a2, a3)),
                                   fmaxf(a4, sc[3][3]));
                if (mz && __all(pmax <= 8.0f)) {
                    #pragma unroll
                    for (int nf = 0; nf < 4; ++nf)
                        #pragma unroll
                        for (int r = 0; r < 4; ++r)
                            sc[nf][r] = __builtin_exp2f(sc[nf][r]);
                } else {
                    mz = false;
                    float mx = pmax;
                    mx = fmaxf(mx, __shfl_xor(mx, 16, 64));
                    mx = fmaxf(mx, __shfl_xor(mx, 32, 64));
                    float mnew = fmaxf(m_run, mx);
                    float fs = __builtin_exp2f(m_run - mnew);
                    m_run = mnew;
                    #pragma unroll
                    for (int nf = 0; nf < 4; ++nf)
                        #pragma unroll
                        for (int r = 0; r < 4; ++r)
                            sc[nf][r] = __builtin_exp2f(sc[nf][r] - mnew);
                    #pragma unroll
                    for (int r = 0; r < 4; ++r) {
                        float fsa = __shfl(fs, lg * 4 + r, 64);
                        #pragma unroll
                        for (int d = 0; d < 4; ++d) acc_o[d][r] *= fsa;
                        acc_l[r] *= fsa;
                    }
                }
                // pack P in-register; PV + l via MFMA
                #pragma unroll
                for (int h2 = 0; h2 < 2; ++h2) {
                    union { i32x4 i; bfx8 b; } pa;
                    pa.i[0] = cvtpk(sc[2 * h2][0],     sc[2 * h2][1]);
                    pa.i[1] = cvtpk(sc[2 * h2][2],     sc[2 * h2][3]);
                    pa.i[2] = cvtpk(sc[2 * h2 + 1][0], sc[2 * h2 + 1][1]);
                    pa.i[3] = cvtpk(sc[2 * h2 + 1][2], sc[2 * h2 + 1][3]);
                    __builtin_amdgcn_s_setprio(1);
                    acc_l = __builtin_amdgcn_mfma_f32_16x16x32_bf16(pa.b, ones, acc_l, 0, 0, 0);
                    #pragma unroll
                    for (int d = 0; d < 4; ++d) {
                        int i = d * 16 + lr;
                        int pv = ((h2 << 2) | lg) ^ (lr & 7);
                        bfx8 bv0 = *reinterpret_cast<const bfx8*>(&sV[cur][s * 4096 + i * 64 + pv * 8]);
                        acc_o[d] = __builtin_amdgcn_mfma_f32_16x16x32_bf16(pa.b, bv0, acc_o[d], 0, 0, 0);
                    }
                    __builtin_amdgcn_s_setprio(0);
                }
            }
            // ---- write pair u+1 into the other buffer, issue loads for u+2
            if (u + 1 < npairs) {
                #pragma unroll
                for (int s = 0; s < 2; ++s) {
                    *reinterpret_cast<u16x8*>(&sK[cur ^ 1][s * 4096 + woff]) = rk[s];
                    *reinterpret_cast<u16x8*>(&sV[cur ^ 1][s * 4096 + woff]) = rv[s];
                }
                if (u + 2 < npairs) {
                    #pragma unroll
                    for (int s = 0; s < 2; ++s) {
                        const int kk = (2 * u + 4 + s) * 64;
                        rk[s] = *reinterpret_cast<const u16x8*>(
                            &K[(rowbase + kk + sig) * DMODEL + hcol + sc8 * 8]);
                        rv[s] = *reinterpret_cast<const u16x8*>(
                            &Vt[((size_t)bh * DH + srow) * SS + kk + sc8 * 8]);
                    }
                }
            }
            __syncthreads();
        }

        // ---- epilogue: shuffle-free (acc_l shares acc_o's C-layout rows)
        f32x4 linv;
        #pragma unroll
        for (int r = 0; r < 4; ++r) linv[r] = 1.0f / acc_l[r];
        const int qrb = q0 + wave * 16 + lg * 4;
        #pragma unroll
        for (int d = 0; d < 4; ++d) {
            int col = hcol + d * 16 + lr;
            #pragma unroll
            for (int r = 0; r < 4; ++r)
                C[(rowbase + qrb + r) * DMODEL + col] = f2bf(acc_o[d][r] * linv[r]);
        }
    }
}

// ---------------------------------------------------------------------------
extern "C" void kernel_launch(void* const* d_in, const int* in_sizes, int n_in,
                              void* d_out, int out_size, void* d_ws, size_t ws_size,
                              hipStream_t stream)
{
    const float* q  = (const float*)d_in[0];
    const float* k  = (const float*)d_in[1];
    const float* v  = (const float*)d_in[2];
    const float* Wq = (const float*)d_in[3];
    const float* bq = (const float*)d_in[4];
    const float* Wk = (const float*)d_in[5];
    const float* bk = (const float*)d_in[6];
    const float* Wv = (const float*)d_in[7];
    const float* bv = (const float*)d_in[8];
    const float* Wf = (const float*)d_in[9];
    const float* bf = (const float*)d_in[10];

    unsigned short* ws = (unsigned short*)d_ws;
    const size_t SZ = (size_t)MROWS * DMODEL;        // 8388608 elems
    unsigned short* Vt = ws;                         // [0, SZ)   V^T per head
    unsigned short* Cb = ws + SZ;                    // [SZ, 2SZ) attn out
    unsigned short* Kb = ws + 3 * SZ;                // [3SZ,4SZ) K projection

    unsigned short* scr = (unsigned short*)d_out;    // d_out as scratch (16M ushorts)
    unsigned short* WqT = scr;                       // [0,1M)
    unsigned short* WkT = scr + 1048576;             // [1M,2M)
    unsigned short* WvT = scr + 2097152;             // [2M,3M)
    unsigned short* WfT = scr + 3145728;             // [3M,4M)
    unsigned short* Qb  = scr + 4194304;             // [4M,12M)

    const float qscale = 0.02209708691207961f * 1.44269504088896341f;

    // 1. all four weight transposes in one launch
    transpose_cvt4_kernel<<<dim3(16, 16, 4), 256, 0, stream>>>(
        Wq, WqT, Wk, WkT, Wv, WvT, Wf, WfT);

    // 2. Q, K, V projections in ONE z=3 launch, fp32 A with fused convert,
    //    async A prefetch, and double-buffered B staging.
    {
        GArg gq{q, WqT, bq, Qb, qscale, 0};
        GArg gk{k, WkT, bk, Kb, 1.0f,   0};
        GArg gv{v, WvT, bv, Vt, 1.0f,   3};
        gemm_kernel<true><<<dim3(64, 8, 3), 256, 0, stream>>>(
            gq, gk, gv, MROWS, DMODEL, DMODEL);
    }

    // 3. attention: Qb, Kb, Vt -> Cb
    attn_kernel<<<dim3(BB * NHEAD, 8), 512, 0, stream>>>(Qb, Kb, Vt, Cb);

    // 4. output projection: Cb @ WfT + bf -> d_out fp32 (scratch regions dead)
    {
        GArg gf{Cb, WfT, bf, (float*)d_out, 1.0f, 2};
        gemm_kernel<false><<<dim3(64, 8, 1), 256, 0, stream>>>(
            gf, gf, gf, MROWS, DMODEL, DMODEL);
    }
}